// Round 1
// baseline (1478.201 us; speedup 1.0000x reference)
//
#include <hip/hip_runtime.h>
#include <math.h>

#define SEQ   2048
#define DM    1024
#define MTOT  4096      // batch * seq
#define NHEAD 16
#define DHEAD 64
#define ROPE_C 0.41524101186091903f   // log2(10000)/32

// ---------------- GEMM: C[M,N] = A[M,K] @ B[N,K]^T, optional fused RoPE ----------------
// 64x64 tile, BK=16, 256 threads, 4x4 acc per thread.
__device__ __forceinline__ void gemm64_body(
    const float* __restrict__ A, const float* __restrict__ B,
    float* __restrict__ C, const int* __restrict__ pos, const bool do_rope)
{
    __shared__ float As[16][68];   // [k][m], +4 pad keeps rows 16B-aligned (272B)
    __shared__ float Bs[16][68];   // [k][n]

    const int tid  = threadIdx.x;
    const int ty   = tid >> 4;        // 0..15 -> rows ty*4..+3
    const int tx   = tid & 15;        // 0..15 -> cols tx*4..+3
    const int row0 = blockIdx.y * 64;
    const int col0 = blockIdx.x * 64;
    const int lr   = tid >> 2;        // 0..63 load row
    const int lc   = (tid & 3) << 2;  // 0,4,8,12 load k-offset

    const float* Ap = A + (size_t)(row0 + lr) * DM + lc;
    const float* Bp = B + (size_t)(col0 + lr) * DM + lc;

    float acc[4][4] = {};

    for (int k0 = 0; k0 < DM; k0 += 16) {
        const float4 av = *(const float4*)(Ap + k0);
        const float4 bv = *(const float4*)(Bp + k0);
        As[lc + 0][lr] = av.x; As[lc + 1][lr] = av.y;
        As[lc + 2][lr] = av.z; As[lc + 3][lr] = av.w;
        Bs[lc + 0][lr] = bv.x; Bs[lc + 1][lr] = bv.y;
        Bs[lc + 2][lr] = bv.z; Bs[lc + 3][lr] = bv.w;
        __syncthreads();
        #pragma unroll
        for (int kk = 0; kk < 16; ++kk) {
            const float4 a = *(const float4*)&As[kk][ty << 2];
            const float4 b = *(const float4*)&Bs[kk][tx << 2];
            const float ar[4] = {a.x, a.y, a.z, a.w};
            const float br[4] = {b.x, b.y, b.z, b.w};
            #pragma unroll
            for (int i = 0; i < 4; ++i)
                #pragma unroll
                for (int j = 0; j < 4; ++j)
                    acc[i][j] += ar[i] * br[j];
        }
        __syncthreads();
    }

    #pragma unroll
    for (int i = 0; i < 4; ++i) {
        const int grow = row0 + (ty << 2) + i;
        float o0 = acc[i][0], o1 = acc[i][1], o2 = acc[i][2], o3 = acc[i][3];
        if (do_rope) {
            // head-local pairs (2p, 2p+1); cols tx*4..+3 hold two full pairs
            const float p = (float)pos[grow & (SEQ - 1)];
            const int cb = col0 + (tx << 2);
            {
                const int ip = (cb & 63) >> 1;
                float sn, cs;
                sincosf(p * exp2f(-(float)ip * ROPE_C), &sn, &cs);
                const float x1 = o0, x2 = o1;
                o0 = x1 * cs - x2 * sn;
                o1 = x2 * cs + x1 * sn;
            }
            {
                const int ip = ((cb + 2) & 63) >> 1;
                float sn, cs;
                sincosf(p * exp2f(-(float)ip * ROPE_C), &sn, &cs);
                const float x1 = o2, x2 = o3;
                o2 = x1 * cs - x2 * sn;
                o3 = x2 * cs + x1 * sn;
            }
        }
        *(float4*)&C[(size_t)grow * DM + col0 + (tx << 2)] = make_float4(o0, o1, o2, o3);
    }
}

__global__ __launch_bounds__(256) void qkv_kernel(
    const float* __restrict__ x, const float* __restrict__ Wq,
    const float* __restrict__ Wk, const float* __restrict__ Wv,
    float* __restrict__ q, float* __restrict__ k, float* __restrict__ v,
    const int* __restrict__ pos)
{
    const int z = blockIdx.z;
    const float* B = (z == 0) ? Wq : (z == 1) ? Wk : Wv;
    float* C       = (z == 0) ? q  : (z == 1) ? k  : v;
    gemm64_body(x, B, C, pos, z < 2);
}

__global__ __launch_bounds__(256) void proj_kernel(
    const float* __restrict__ ao, const float* __restrict__ Wo,
    float* __restrict__ out)
{
    gemm64_body(ao, Wo, out, nullptr, false);
}

// ---------------- Flash-style causal attention, fp32, one (b,h) x 64-row q-tile per block ----
// Thread map: rows R_i = ty*4+i, cols C_j = tx + 16*j (lane-consecutive rows on K-fragment
// reads -> 2-way LDS aliasing only, which is free on gfx950).
__global__ __launch_bounds__(256) void attn_kernel(
    const float* __restrict__ Q, const float* __restrict__ K,
    const float* __restrict__ V, float* __restrict__ O)
{
    __shared__ float Qs[64][68];
    __shared__ float Ks[64][68];   // reused to hold P after scores are consumed
    __shared__ float Vs[64][68];

    const int tid = threadIdx.x;
    const int ty  = tid >> 4;
    const int tx  = tid & 15;
    const int qt  = blockIdx.x;
    const int bh  = blockIdx.y;
    const size_t hoff = (size_t)(bh >> 4) * SEQ * DM + (size_t)(bh & 15) * DHEAD;

    // load Q tile, pre-scaled by 1/sqrt(dh) = 0.125
    #pragma unroll
    for (int idx = tid; idx < 1024; idx += 256) {
        const int r = idx >> 4;
        const int c = (idx & 15) << 2;
        const float4 qv = *(const float4*)&Q[hoff + (size_t)(qt * 64 + r) * DM + c];
        Qs[r][c + 0] = qv.x * 0.125f;
        Qs[r][c + 1] = qv.y * 0.125f;
        Qs[r][c + 2] = qv.z * 0.125f;
        Qs[r][c + 3] = qv.w * 0.125f;
    }

    float m_i[4], l_i[4], oacc[4][4] = {};
    #pragma unroll
    for (int i = 0; i < 4; ++i) { m_i[i] = -INFINITY; l_i[i] = 0.f; }

    for (int kt = 0; kt <= qt; ++kt) {
        #pragma unroll
        for (int idx = tid; idx < 1024; idx += 256) {
            const int r = idx >> 4;
            const int c = (idx & 15) << 2;
            *(float4*)&Ks[r][c] = *(const float4*)&K[hoff + (size_t)(kt * 64 + r) * DM + c];
            *(float4*)&Vs[r][c] = *(const float4*)&V[hoff + (size_t)(kt * 64 + r) * DM + c];
        }
        __syncthreads();

        // S = Q K^T (pre-scaled)
        float s[4][4] = {};
        #pragma unroll
        for (int d4 = 0; d4 < 16; ++d4) {
            float4 qv[4], kv[4];
            #pragma unroll
            for (int i = 0; i < 4; ++i) qv[i] = *(const float4*)&Qs[(ty << 2) + i][d4 << 2];
            #pragma unroll
            for (int j = 0; j < 4; ++j) kv[j] = *(const float4*)&Ks[tx + 16 * j][d4 << 2];
            #pragma unroll
            for (int i = 0; i < 4; ++i)
                #pragma unroll
                for (int j = 0; j < 4; ++j)
                    s[i][j] += qv[i].x * kv[j].x + qv[i].y * kv[j].y +
                               qv[i].z * kv[j].z + qv[i].w * kv[j].w;
        }

        if (kt == qt) {   // causal mask on the diagonal tile
            #pragma unroll
            for (int i = 0; i < 4; ++i)
                #pragma unroll
                for (int j = 0; j < 4; ++j)
                    if (tx + 16 * j > (ty << 2) + i) s[i][j] = -INFINITY;
        }

        // online softmax; the 16 tx-lanes of a row group reduce over lane bits 0..3
        #pragma unroll
        for (int i = 0; i < 4; ++i) {
            float rmax = fmaxf(fmaxf(s[i][0], s[i][1]), fmaxf(s[i][2], s[i][3]));
            #pragma unroll
            for (int off = 1; off < 16; off <<= 1)
                rmax = fmaxf(rmax, __shfl_xor(rmax, off, 64));
            const float mn    = fmaxf(m_i[i], rmax);
            const float alpha = __expf(m_i[i] - mn);   // exp(-inf)=0 handles first tile
            float rsum = 0.f;
            #pragma unroll
            for (int j = 0; j < 4; ++j) { s[i][j] = __expf(s[i][j] - mn); rsum += s[i][j]; }
            #pragma unroll
            for (int off = 1; off < 16; off <<= 1)
                rsum += __shfl_xor(rsum, off, 64);
            l_i[i] = l_i[i] * alpha + rsum;
            m_i[i] = mn;
            #pragma unroll
            for (int j = 0; j < 4; ++j) oacc[i][j] *= alpha;
        }

        __syncthreads();   // all waves done reading Ks as scores input
        #pragma unroll
        for (int i = 0; i < 4; ++i)
            #pragma unroll
            for (int j = 0; j < 4; ++j)
                Ks[(ty << 2) + i][tx + 16 * j] = s[i][j];
        __syncthreads();   // P visible to all

        // O += P V
        #pragma unroll
        for (int c4 = 0; c4 < 16; ++c4) {
            float4 pr[4];
            #pragma unroll
            for (int i = 0; i < 4; ++i) pr[i] = *(const float4*)&Ks[(ty << 2) + i][c4 << 2];
            float vv[4][4];
            #pragma unroll
            for (int cc = 0; cc < 4; ++cc)
                #pragma unroll
                for (int j = 0; j < 4; ++j)
                    vv[cc][j] = Vs[(c4 << 2) + cc][tx + 16 * j];
            #pragma unroll
            for (int i = 0; i < 4; ++i) {
                const float pa[4] = {pr[i].x, pr[i].y, pr[i].z, pr[i].w};
                #pragma unroll
                for (int j = 0; j < 4; ++j)
                    oacc[i][j] += pa[0] * vv[0][j] + pa[1] * vv[1][j] +
                                  pa[2] * vv[2][j] + pa[3] * vv[3][j];
            }
        }
        __syncthreads();   // Ks/Vs free for next tile
    }

    #pragma unroll
    for (int i = 0; i < 4; ++i) {
        const float invl = 1.0f / l_i[i];
        const size_t rbase = hoff + (size_t)(qt * 64 + (ty << 2) + i) * DM;
        #pragma unroll
        for (int j = 0; j < 4; ++j)
            O[rbase + tx + 16 * j] = oacc[i][j] * invl;
    }
}

extern "C" void kernel_launch(void* const* d_in, const int* in_sizes, int n_in,
                              void* d_out, int out_size, void* d_ws, size_t ws_size,
                              hipStream_t stream)
{
    const float* x  = (const float*)d_in[0];
    const int*  pos = (const int*)d_in[1];
    const float* Wq = (const float*)d_in[2];
    const float* Wk = (const float*)d_in[3];
    const float* Wv = (const float*)d_in[4];
    const float* Wo = (const float*)d_in[5];
    float* out = (float*)d_out;

    float* q  = (float*)d_ws;                 // 4 buffers x 16 MB = 64 MB of ws
    float* k  = q + (size_t)MTOT * DM;
    float* v  = k + (size_t)MTOT * DM;
    float* ao = v + (size_t)MTOT * DM;

    qkv_kernel<<<dim3(DM / 64, MTOT / 64, 3), 256, 0, stream>>>(x, Wq, Wk, Wv, q, k, v, pos);
    attn_kernel<<<dim3(SEQ / 64, 2 * NHEAD), 256, 0, stream>>>(q, k, v, ao);
    proj_kernel<<<dim3(DM / 64, MTOT / 64), 256, 0, stream>>>(ao, Wo, out);
}

// Round 2
// 662.788 us; speedup vs baseline: 2.2303x; 2.2303x over previous
//
#include <hip/hip_runtime.h>
#include <math.h>

#define SEQ   2048
#define DM    1024
#define MTOT  4096      // batch * seq
#define NHEAD 16
#define DHEAD 64
#define ROPE_C 0.41524101186091903f   // log2(10000)/32

typedef __bf16 bf16x8 __attribute__((ext_vector_type(8)));
typedef float  f32x4  __attribute__((ext_vector_type(4)));

// ---------------- fp32 GEMM: C = A[M,K] @ B[N,K]^T, 64x64 tile, epilogue by MODE ------
// MODE 0: RoPE + 0.125 scale, bf16 out (q)   MODE 1: RoPE, bf16 out (k)
// MODE 2: bf16 out transposed to [b][h][dh][seq] (v)   MODE 3: fp32 out (proj)
template <int MODE>
__device__ __forceinline__ void gemm64_body(
    const float* __restrict__ A, const float* __restrict__ B,
    void* __restrict__ Cv, const int* __restrict__ pos)
{
    __shared__ float As[16][68];
    __shared__ float Bs[16][68];

    const int tid  = threadIdx.x;
    const int ty   = tid >> 4;
    const int tx   = tid & 15;
    const int row0 = blockIdx.y * 64;
    const int col0 = blockIdx.x * 64;
    const int lr   = tid >> 2;
    const int lc   = (tid & 3) << 2;

    const float* Ap = A + (size_t)(row0 + lr) * DM + lc;
    const float* Bp = B + (size_t)(col0 + lr) * DM + lc;

    float acc[4][4] = {};

    for (int k0 = 0; k0 < DM; k0 += 16) {
        const float4 av = *(const float4*)(Ap + k0);
        const float4 bv = *(const float4*)(Bp + k0);
        As[lc + 0][lr] = av.x; As[lc + 1][lr] = av.y;
        As[lc + 2][lr] = av.z; As[lc + 3][lr] = av.w;
        Bs[lc + 0][lr] = bv.x; Bs[lc + 1][lr] = bv.y;
        Bs[lc + 2][lr] = bv.z; Bs[lc + 3][lr] = bv.w;
        __syncthreads();
        #pragma unroll
        for (int kk = 0; kk < 16; ++kk) {
            const float4 a = *(const float4*)&As[kk][ty << 2];
            const float4 b = *(const float4*)&Bs[kk][tx << 2];
            const float ar[4] = {a.x, a.y, a.z, a.w};
            const float br[4] = {b.x, b.y, b.z, b.w};
            #pragma unroll
            for (int i = 0; i < 4; ++i)
                #pragma unroll
                for (int j = 0; j < 4; ++j)
                    acc[i][j] += ar[i] * br[j];
        }
        __syncthreads();
    }

    #pragma unroll
    for (int i = 0; i < 4; ++i) {
        const int grow = row0 + (ty << 2) + i;
        float o0 = acc[i][0], o1 = acc[i][1], o2 = acc[i][2], o3 = acc[i][3];
        if (MODE <= 1) {
            const float p = (float)pos[grow & (SEQ - 1)];
            const int cb = col0 + (tx << 2);
            {
                const int ip = (cb & 63) >> 1;
                float sn, cs;
                sincosf(p * exp2f(-(float)ip * ROPE_C), &sn, &cs);
                const float x1 = o0, x2 = o1;
                o0 = x1 * cs - x2 * sn;
                o1 = x2 * cs + x1 * sn;
            }
            {
                const int ip = ((cb + 2) & 63) >> 1;
                float sn, cs;
                sincosf(p * exp2f(-(float)ip * ROPE_C), &sn, &cs);
                const float x1 = o2, x2 = o3;
                o2 = x1 * cs - x2 * sn;
                o3 = x2 * cs + x1 * sn;
            }
            if (MODE == 0) { o0 *= 0.125f; o1 *= 0.125f; o2 *= 0.125f; o3 *= 0.125f; }
            __bf16 w[4] = {(__bf16)o0, (__bf16)o1, (__bf16)o2, (__bf16)o3};
            *(float2*)&((__bf16*)Cv)[(size_t)grow * DM + col0 + (tx << 2)] = *(float2*)w;
        } else if (MODE == 2) {
            const int b_ = grow >> 11, sidx = grow & (SEQ - 1);
            const float oo[4] = {o0, o1, o2, o3};
            #pragma unroll
            for (int j = 0; j < 4; ++j) {
                const int col = col0 + (tx << 2) + j;
                const int h = col >> 6, d = col & 63;
                ((__bf16*)Cv)[((size_t)((b_ << 4) + h) * 64 + d) * SEQ + sidx] = (__bf16)oo[j];
            }
        } else {
            *(float4*)&((float*)Cv)[(size_t)grow * DM + col0 + (tx << 2)] =
                make_float4(o0, o1, o2, o3);
        }
    }
}

__global__ __launch_bounds__(256) void qkv_kernel(
    const float* __restrict__ x, const float* __restrict__ Wq,
    const float* __restrict__ Wk, const float* __restrict__ Wv,
    __bf16* __restrict__ q, __bf16* __restrict__ k, __bf16* __restrict__ vt,
    const int* __restrict__ pos)
{
    const int z = blockIdx.z;
    if (z == 0)      gemm64_body<0>(x, Wq, q,  pos);
    else if (z == 1) gemm64_body<1>(x, Wk, k,  pos);
    else             gemm64_body<2>(x, Wv, vt, pos);
}

__global__ __launch_bounds__(256) void proj_kernel(
    const float* __restrict__ ao, const float* __restrict__ Wo,
    float* __restrict__ out)
{
    gemm64_body<3>(ao, Wo, out, nullptr);
}

// ---------------- MFMA flash attention, bf16 inputs, fp32 accum -----------------------
// Block: 4 waves, 64 q-rows, one (b,h). Wave w owns q-rows [w*16, w*16+16).
// 16x16x32 bf16 MFMA. LDS rows padded to 72 bf16 (144 B) -> b128-aligned, 2-way bank
// aliasing only (free). P round-trips through wave-private LDS (C-layout -> A-layout).
__global__ __launch_bounds__(256, 4) void attn_kernel(
    const __bf16* __restrict__ Q, const __bf16* __restrict__ K,
    const __bf16* __restrict__ Vt, float* __restrict__ O)
{
    __shared__ __bf16 Qs[64][72];
    __shared__ __bf16 Ks[64][72];
    __shared__ __bf16 Vs[64][72];       // [dh][key]
    __shared__ __bf16 Ps[4][16][72];    // wave-private P tiles

    const int tid  = threadIdx.x;
    const int wave = tid >> 6;
    const int lane = tid & 63;
    const int lq   = lane & 15;
    const int quad = lane >> 4;
    const int qt = blockIdx.x, bh = blockIdx.y;
    const int b = bh >> 4, h = bh & 15;
    const size_t qkoff = (size_t)b * SEQ * DM + h * 64;
    const size_t vtoff = (size_t)bh * 64 * SEQ;

    const int r_ = tid >> 2, c_ = (tid & 3) << 4;
    {   // stage Q tile once
        const __bf16* gp = Q + qkoff + (size_t)(qt * 64 + r_) * DM + c_;
        *(float4*)&Qs[r_][c_]     = *(const float4*)gp;
        *(float4*)&Qs[r_][c_ + 8] = *(const float4*)(gp + 8);
    }
    __syncthreads();

    const bf16x8 aq0 = *(const bf16x8*)&Qs[wave * 16 + lq][quad * 8];
    const bf16x8 aq1 = *(const bf16x8*)&Qs[wave * 16 + lq][32 + quad * 8];

    f32x4 o[4] = {};
    float m_i[4], l_i[4];
    #pragma unroll
    for (int r = 0; r < 4; ++r) { m_i[r] = -INFINITY; l_i[r] = 0.f; }

    const __bf16* kg = K  + qkoff + (size_t)r_ * DM  + c_;
    const __bf16* vg = Vt + vtoff + (size_t)r_ * SEQ + c_;

    for (int kt = 0; kt <= qt; ++kt) {
        __syncthreads();   // previous iteration's reads of Ks/Vs complete
        {
            const __bf16* kp = kg + (size_t)kt * 64 * DM;
            const __bf16* vp = vg + kt * 64;
            *(float4*)&Ks[r_][c_]     = *(const float4*)kp;
            *(float4*)&Ks[r_][c_ + 8] = *(const float4*)(kp + 8);
            *(float4*)&Vs[r_][c_]     = *(const float4*)vp;
            *(float4*)&Vs[r_][c_ + 8] = *(const float4*)(vp + 8);
        }
        __syncthreads();

        // S = Q K^T  (Q pre-scaled by 1/8)
        f32x4 s[4] = {};
        #pragma unroll
        for (int nt = 0; nt < 4; ++nt) {
            const bf16x8 bk0 = *(const bf16x8*)&Ks[lq + 16 * nt][quad * 8];
            const bf16x8 bk1 = *(const bf16x8*)&Ks[lq + 16 * nt][32 + quad * 8];
            s[nt] = __builtin_amdgcn_mfma_f32_16x16x32_bf16(aq0, bk0, s[nt], 0, 0, 0);
            s[nt] = __builtin_amdgcn_mfma_f32_16x16x32_bf16(aq1, bk1, s[nt], 0, 0, 0);
        }

        if (kt == qt) {    // causal mask on diagonal tile
            const int myrow = wave * 16 + quad * 4;
            #pragma unroll
            for (int nt = 0; nt < 4; ++nt)
                #pragma unroll
                for (int r = 0; r < 4; ++r)
                    if (lq + 16 * nt > myrow + r) s[nt][r] = -INFINITY;
        }

        // online softmax: row = quad*4 + r, cols spread over lane bits 0..3 and nt
        #pragma unroll
        for (int r = 0; r < 4; ++r) {
            float sm = fmaxf(fmaxf(s[0][r], s[1][r]), fmaxf(s[2][r], s[3][r]));
            sm = fmaxf(sm, __shfl_xor(sm, 1, 64));
            sm = fmaxf(sm, __shfl_xor(sm, 2, 64));
            sm = fmaxf(sm, __shfl_xor(sm, 4, 64));
            sm = fmaxf(sm, __shfl_xor(sm, 8, 64));
            const float mn    = fmaxf(m_i[r], sm);
            const float alpha = __expf(m_i[r] - mn);   // exp(-inf)=0 on first tile
            m_i[r] = mn;
            float rs = 0.f;
            #pragma unroll
            for (int nt = 0; nt < 4; ++nt) { s[nt][r] = __expf(s[nt][r] - mn); rs += s[nt][r]; }
            rs += __shfl_xor(rs, 1, 64);
            rs += __shfl_xor(rs, 2, 64);
            rs += __shfl_xor(rs, 4, 64);
            rs += __shfl_xor(rs, 8, 64);
            l_i[r] = l_i[r] * alpha + rs;
            #pragma unroll
            for (int nt = 0; nt < 4; ++nt) o[nt][r] *= alpha;
        }

        // P: C-layout regs -> wave-private LDS [qrow][key] (bf16)
        #pragma unroll
        for (int nt = 0; nt < 4; ++nt)
            #pragma unroll
            for (int r = 0; r < 4; ++r)
                Ps[wave][quad * 4 + r][lq + 16 * nt] = (__bf16)s[nt][r];

        // O += P V   (A-frags from Ps, B-frags from transposed Vs)
        const bf16x8 ap0 = *(const bf16x8*)&Ps[wave][lq][quad * 8];
        const bf16x8 ap1 = *(const bf16x8*)&Ps[wave][lq][32 + quad * 8];
        #pragma unroll
        for (int nt = 0; nt < 4; ++nt) {
            const bf16x8 bv0 = *(const bf16x8*)&Vs[lq + 16 * nt][quad * 8];
            const bf16x8 bv1 = *(const bf16x8*)&Vs[lq + 16 * nt][32 + quad * 8];
            o[nt] = __builtin_amdgcn_mfma_f32_16x16x32_bf16(ap0, bv0, o[nt], 0, 0, 0);
            o[nt] = __builtin_amdgcn_mfma_f32_16x16x32_bf16(ap1, bv1, o[nt], 0, 0, 0);
        }
    }

    #pragma unroll
    for (int r = 0; r < 4; ++r) {
        const float invl = 1.f / l_i[r];
        const size_t row = (size_t)b * SEQ + qt * 64 + wave * 16 + quad * 4 + r;
        float* op = O + row * DM + h * 64 + lq;
        #pragma unroll
        for (int nt = 0; nt < 4; ++nt)
            op[16 * nt] = o[nt][r] * invl;
    }
}

extern "C" void kernel_launch(void* const* d_in, const int* in_sizes, int n_in,
                              void* d_out, int out_size, void* d_ws, size_t ws_size,
                              hipStream_t stream)
{
    const float* x  = (const float*)d_in[0];
    const int*  pos = (const int*)d_in[1];
    const float* Wq = (const float*)d_in[2];
    const float* Wk = (const float*)d_in[3];
    const float* Wv = (const float*)d_in[4];
    const float* Wo = (const float*)d_in[5];
    float* out = (float*)d_out;

    __bf16* q  = (__bf16*)d_ws;                      // 8 MB
    __bf16* k  = q + (size_t)MTOT * DM;              // 8 MB
    __bf16* vt = k + (size_t)MTOT * DM;              // 8 MB, [b][h][dh][seq]
    float*  ao = (float*)(vt + (size_t)MTOT * DM);   // 16 MB

    qkv_kernel<<<dim3(DM / 64, MTOT / 64, 3), 256, 0, stream>>>(x, Wq, Wk, Wv, q, k, vt, pos);
    attn_kernel<<<dim3(SEQ / 64, 2 * NHEAD), 256, 0, stream>>>(q, k, vt, ao);
    proj_kernel<<<dim3(DM / 64, MTOT / 64), 256, 0, stream>>>(ao, Wo, out);
}

// Round 3
// 498.591 us; speedup vs baseline: 2.9648x; 1.3293x over previous
//
#include <hip/hip_runtime.h>
#include <math.h>

#define SEQ   2048
#define DM    1024
#define MTOT  4096      // batch * seq
#define NHEAD 16
#define DHEAD 64
#define ROPE_C 0.41524101186091903f   // log2(10000)/32
#define XN    (MTOT * DM)             // 4194304
#define WN    (DM * DM)               // 1048576

typedef __bf16 bf16x8 __attribute__((ext_vector_type(8)));
typedef float  f32x4  __attribute__((ext_vector_type(4)));

// async global->LDS, 16 B/lane; lds dest = wave-uniform base + lane*16
__device__ __forceinline__ void gll16(const __bf16* gp, __bf16* lp) {
    __builtin_amdgcn_global_load_lds(
        (const __attribute__((address_space(1))) unsigned int*)gp,
        (__attribute__((address_space(3))) unsigned int*)lp,
        16, 0, 0);
}

// ---------------- fp32 -> bf16 conversion of x and the 4 weight matrices --------------
__global__ __launch_bounds__(256) void cvt_kernel(
    const float* __restrict__ x,  const float* __restrict__ wq,
    const float* __restrict__ wk, const float* __restrict__ wv,
    const float* __restrict__ wo,
    __bf16* __restrict__ xb,  __bf16* __restrict__ wqb,
    __bf16* __restrict__ wkb, __bf16* __restrict__ wvb,
    __bf16* __restrict__ wob)
{
    const size_t i8 = ((size_t)blockIdx.x * 256 + threadIdx.x) * 8;
    const float* s; __bf16* d; size_t off;
    if      (i8 < XN)          { s = x;  d = xb;  off = i8; }
    else if (i8 < XN + WN)     { s = wq; d = wqb; off = i8 - XN; }
    else if (i8 < XN + 2 * WN) { s = wk; d = wkb; off = i8 - XN - 2 * (size_t)WN + WN; }
    else if (i8 < XN + 3 * WN) { s = wv; d = wvb; off = i8 - XN - 2 * (size_t)WN; }
    else                       { s = wo; d = wob; off = i8 - XN - 3 * (size_t)WN; }
    const float4 a = *(const float4*)(s + off);
    const float4 b = *(const float4*)(s + off + 4);
    __bf16 o[8] = {(__bf16)a.x, (__bf16)a.y, (__bf16)a.z, (__bf16)a.w,
                   (__bf16)b.x, (__bf16)b.y, (__bf16)b.z, (__bf16)b.w};
    *(float4*)(d + off) = *(float4*)o;
}

// ---------------- MFMA GEMM: C[M,1024] = A[M,1024] @ B[1024,1024]^T -------------------
// 128x128 tile, BK=32, 256 threads (2x2 waves, 4x4 16x16x32 MFMAs each).
// LDS unpadded (global_load_lds requires contiguous lane order).
// MODE 0: RoPE+0.125, bf16 (q)  MODE 1: RoPE, bf16 (k)
// MODE 2: bf16 transposed to [b][h][dh][seq] (v)  MODE 3: fp32 (proj out)
template <int MODE>
__device__ __forceinline__ void mfma_gemm_body(
    const __bf16* __restrict__ A, const __bf16* __restrict__ B,
    void* __restrict__ Cv, const int* __restrict__ pos)
{
    __shared__ __align__(16) __bf16 As[128 * 32];
    __shared__ __align__(16) __bf16 Bs[128 * 32];

    const int tid  = threadIdx.x;
    const int wave = tid >> 6, lane = tid & 63;
    const int lq   = lane & 15, quad = lane >> 4;
    const int row0 = blockIdx.y * 128, col0 = blockIdx.x * 128;
    const int mb   = (wave >> 1) * 64, nb = (wave & 1) * 64;

    // staging: wave w covers LDS elems [w*1024 + i*512), i=0,1 ; lane -> 8 bf16
    const int srow = wave * 32 + (lane >> 2);   // +16 for i=1
    const int scol = (lane & 3) << 3;
    const __bf16* Ag = A + (size_t)(row0 + srow) * DM + scol;
    const __bf16* Bg = B + (size_t)(col0 + srow) * DM + scol;
    __bf16* Al = As + wave * 1024;
    __bf16* Bl = Bs + wave * 1024;

    f32x4 acc[4][4] = {};

    for (int k0 = 0; k0 < DM; k0 += 32) {
        gll16(Ag + k0,             Al);
        gll16(Ag + k0 + 16 * DM,   Al + 512);
        gll16(Bg + k0,             Bl);
        gll16(Bg + k0 + 16 * DM,   Bl + 512);
        __syncthreads();   // drains vmcnt -> async LDS writes visible

        bf16x8 af[4], bfr[4];
        #pragma unroll
        for (int mt = 0; mt < 4; ++mt)
            af[mt] = *(const bf16x8*)&As[(mb + mt * 16 + lq) * 32 + quad * 8];
        #pragma unroll
        for (int nt = 0; nt < 4; ++nt)
            bfr[nt] = *(const bf16x8*)&Bs[(nb + nt * 16 + lq) * 32 + quad * 8];
        #pragma unroll
        for (int mt = 0; mt < 4; ++mt)
            #pragma unroll
            for (int nt = 0; nt < 4; ++nt)
                acc[mt][nt] = __builtin_amdgcn_mfma_f32_16x16x32_bf16(
                    af[mt], bfr[nt], acc[mt][nt], 0, 0, 0);
        __syncthreads();   // all reads done before next overwrite
    }

    #pragma unroll
    for (int mt = 0; mt < 4; ++mt) {
        #pragma unroll
        for (int r = 0; r < 4; ++r) {
            const int grow = row0 + mb + mt * 16 + quad * 4 + r;
            if (MODE <= 1) {
                const float p = (float)pos[grow & (SEQ - 1)];
                #pragma unroll
                for (int nt = 0; nt < 4; ++nt) {
                    const int gcol = col0 + nb + nt * 16 + lq;
                    const float v   = acc[mt][nt][r];
                    const float prt = __shfl_xor(v, 1, 64);  // pair partner (col^1)
                    const int ip = (gcol & 63) >> 1;
                    float sn, cs;
                    sincosf(p * exp2f(-(float)ip * ROPE_C), &sn, &cs);
                    float o = (lq & 1) ? (v * cs + prt * sn) : (v * cs - prt * sn);
                    if (MODE == 0) o *= 0.125f;
                    ((__bf16*)Cv)[(size_t)grow * DM + gcol] = (__bf16)o;
                }
            } else if (MODE == 2) {
                const int b_ = grow >> 11, sidx = grow & (SEQ - 1);
                #pragma unroll
                for (int nt = 0; nt < 4; ++nt) {
                    const int gcol = col0 + nb + nt * 16 + lq;
                    const int h = gcol >> 6, d = gcol & 63;
                    ((__bf16*)Cv)[((size_t)((b_ << 4) + h) * 64 + d) * SEQ + sidx] =
                        (__bf16)acc[mt][nt][r];
                }
            } else {
                #pragma unroll
                for (int nt = 0; nt < 4; ++nt) {
                    const int gcol = col0 + nb + nt * 16 + lq;
                    ((float*)Cv)[(size_t)grow * DM + gcol] = acc[mt][nt][r];
                }
            }
        }
    }
}

__global__ __launch_bounds__(256) void qkv_kernel(
    const __bf16* __restrict__ xb, const __bf16* __restrict__ wqb,
    const __bf16* __restrict__ wkb, const __bf16* __restrict__ wvb,
    __bf16* __restrict__ q, __bf16* __restrict__ k, __bf16* __restrict__ vt,
    const int* __restrict__ pos)
{
    const int z = blockIdx.z;
    if (z == 0)      mfma_gemm_body<0>(xb, wqb, q,  pos);
    else if (z == 1) mfma_gemm_body<1>(xb, wkb, k,  pos);
    else             mfma_gemm_body<2>(xb, wvb, vt, pos);
}

__global__ __launch_bounds__(256) void proj_kernel(
    const __bf16* __restrict__ aob, const __bf16* __restrict__ wob,
    float* __restrict__ out)
{
    mfma_gemm_body<3>(aob, wob, out, nullptr);
}

// ---------------- MFMA flash attention, bf16 in, fp32 accum, bf16 out ----------------
__global__ __launch_bounds__(256, 4) void attn_kernel(
    const __bf16* __restrict__ Q, const __bf16* __restrict__ K,
    const __bf16* __restrict__ Vt, __bf16* __restrict__ O)
{
    __shared__ __bf16 Qs[64][72];
    __shared__ __bf16 Ks[64][72];
    __shared__ __bf16 Vs[64][72];       // [dh][key]
    __shared__ __bf16 Ps[4][16][72];    // wave-private P tiles

    const int tid  = threadIdx.x;
    const int wave = tid >> 6;
    const int lane = tid & 63;
    const int lq   = lane & 15;
    const int quad = lane >> 4;
    const int qt = blockIdx.x, bh = blockIdx.y;
    const int b = bh >> 4, h = bh & 15;
    const size_t qkoff = (size_t)b * SEQ * DM + h * 64;
    const size_t vtoff = (size_t)bh * 64 * SEQ;

    const int r_ = tid >> 2, c_ = (tid & 3) << 4;
    {   // stage Q tile once
        const __bf16* gp = Q + qkoff + (size_t)(qt * 64 + r_) * DM + c_;
        *(float4*)&Qs[r_][c_]     = *(const float4*)gp;
        *(float4*)&Qs[r_][c_ + 8] = *(const float4*)(gp + 8);
    }
    __syncthreads();

    const bf16x8 aq0 = *(const bf16x8*)&Qs[wave * 16 + lq][quad * 8];
    const bf16x8 aq1 = *(const bf16x8*)&Qs[wave * 16 + lq][32 + quad * 8];

    f32x4 o[4] = {};
    float m_i[4], l_i[4];
    #pragma unroll
    for (int r = 0; r < 4; ++r) { m_i[r] = -INFINITY; l_i[r] = 0.f; }

    const __bf16* kg = K  + qkoff + (size_t)r_ * DM  + c_;
    const __bf16* vg = Vt + vtoff + (size_t)r_ * SEQ + c_;

    for (int kt = 0; kt <= qt; ++kt) {
        __syncthreads();
        {
            const __bf16* kp = kg + (size_t)kt * 64 * DM;
            const __bf16* vp = vg + kt * 64;
            *(float4*)&Ks[r_][c_]     = *(const float4*)kp;
            *(float4*)&Ks[r_][c_ + 8] = *(const float4*)(kp + 8);
            *(float4*)&Vs[r_][c_]     = *(const float4*)vp;
            *(float4*)&Vs[r_][c_ + 8] = *(const float4*)(vp + 8);
        }
        __syncthreads();

        f32x4 s[4] = {};
        #pragma unroll
        for (int nt = 0; nt < 4; ++nt) {
            const bf16x8 bk0 = *(const bf16x8*)&Ks[lq + 16 * nt][quad * 8];
            const bf16x8 bk1 = *(const bf16x8*)&Ks[lq + 16 * nt][32 + quad * 8];
            s[nt] = __builtin_amdgcn_mfma_f32_16x16x32_bf16(aq0, bk0, s[nt], 0, 0, 0);
            s[nt] = __builtin_amdgcn_mfma_f32_16x16x32_bf16(aq1, bk1, s[nt], 0, 0, 0);
        }

        if (kt == qt) {
            const int myrow = wave * 16 + quad * 4;
            #pragma unroll
            for (int nt = 0; nt < 4; ++nt)
                #pragma unroll
                for (int r = 0; r < 4; ++r)
                    if (lq + 16 * nt > myrow + r) s[nt][r] = -INFINITY;
        }

        #pragma unroll
        for (int r = 0; r < 4; ++r) {
            float sm = fmaxf(fmaxf(s[0][r], s[1][r]), fmaxf(s[2][r], s[3][r]));
            sm = fmaxf(sm, __shfl_xor(sm, 1, 64));
            sm = fmaxf(sm, __shfl_xor(sm, 2, 64));
            sm = fmaxf(sm, __shfl_xor(sm, 4, 64));
            sm = fmaxf(sm, __shfl_xor(sm, 8, 64));
            const float mn    = fmaxf(m_i[r], sm);
            const float alpha = __expf(m_i[r] - mn);
            m_i[r] = mn;
            float rs = 0.f;
            #pragma unroll
            for (int nt = 0; nt < 4; ++nt) { s[nt][r] = __expf(s[nt][r] - mn); rs += s[nt][r]; }
            rs += __shfl_xor(rs, 1, 64);
            rs += __shfl_xor(rs, 2, 64);
            rs += __shfl_xor(rs, 4, 64);
            rs += __shfl_xor(rs, 8, 64);
            l_i[r] = l_i[r] * alpha + rs;
            #pragma unroll
            for (int nt = 0; nt < 4; ++nt) o[nt][r] *= alpha;
        }

        #pragma unroll
        for (int nt = 0; nt < 4; ++nt)
            #pragma unroll
            for (int r = 0; r < 4; ++r)
                Ps[wave][quad * 4 + r][lq + 16 * nt] = (__bf16)s[nt][r];

        const bf16x8 ap0 = *(const bf16x8*)&Ps[wave][lq][quad * 8];
        const bf16x8 ap1 = *(const bf16x8*)&Ps[wave][lq][32 + quad * 8];
        #pragma unroll
        for (int nt = 0; nt < 4; ++nt) {
            const bf16x8 bv0 = *(const bf16x8*)&Vs[lq + 16 * nt][quad * 8];
            const bf16x8 bv1 = *(const bf16x8*)&Vs[lq + 16 * nt][32 + quad * 8];
            o[nt] = __builtin_amdgcn_mfma_f32_16x16x32_bf16(ap0, bv0, o[nt], 0, 0, 0);
            o[nt] = __builtin_amdgcn_mfma_f32_16x16x32_bf16(ap1, bv1, o[nt], 0, 0, 0);
        }
    }

    #pragma unroll
    for (int r = 0; r < 4; ++r) {
        const float invl = 1.f / l_i[r];
        const size_t row = (size_t)b * SEQ + qt * 64 + wave * 16 + quad * 4 + r;
        __bf16* op = O + row * DM + h * 64 + lq;
        #pragma unroll
        for (int nt = 0; nt < 4; ++nt)
            op[16 * nt] = (__bf16)(o[nt][r] * invl);
    }
}

extern "C" void kernel_launch(void* const* d_in, const int* in_sizes, int n_in,
                              void* d_out, int out_size, void* d_ws, size_t ws_size,
                              hipStream_t stream)
{
    const float* x  = (const float*)d_in[0];
    const int*  pos = (const int*)d_in[1];
    const float* Wq = (const float*)d_in[2];
    const float* Wk = (const float*)d_in[3];
    const float* Wv = (const float*)d_in[4];
    const float* Wo = (const float*)d_in[5];
    float* out = (float*)d_out;

    __bf16* xb  = (__bf16*)d_ws;            // 8 MB
    __bf16* wqb = xb  + (size_t)XN;         // 2 MB each
    __bf16* wkb = wqb + (size_t)WN;
    __bf16* wvb = wkb + (size_t)WN;
    __bf16* wob = wvb + (size_t)WN;
    __bf16* q   = wob + (size_t)WN;         // 8 MB
    __bf16* k   = q   + (size_t)XN;         // 8 MB
    __bf16* vt  = k   + (size_t)XN;         // 8 MB, [b][h][dh][seq]
    __bf16* aob = vt  + (size_t)XN;         // 8 MB

    cvt_kernel<<<(XN + 4 * WN) / (8 * 256), 256, 0, stream>>>(
        x, Wq, Wk, Wv, Wo, xb, wqb, wkb, wvb, wob);
    qkv_kernel<<<dim3(DM / 128, MTOT / 128, 3), 256, 0, stream>>>(
        xb, wqb, wkb, wvb, q, k, vt, pos);
    attn_kernel<<<dim3(SEQ / 64, 2 * NHEAD), 256, 0, stream>>>(q, k, vt, aob);
    proj_kernel<<<dim3(DM / 128, MTOT / 128), 256, 0, stream>>>(aob, wob, out);
}